// Round 8
// baseline (3155.542 us; speedup 1.0000x reference)
//
#include <hip/hip_runtime.h>

// Problem constants (match reference)
constexpr int NB   = 8;     // batches
constexpr int NC   = 64;    // channels
constexpr int NN   = 8192;  // points
constexpr int NM   = 2048;  // samples
constexpr int NK   = 16;    // knn
constexpr int NFPS = 1433;  // int(2048*0.7)
constexpr int NRAND = NM - NFPS; // 615

// ---------------- workspace layout (bytes) ----------------
constexpr size_t OFF_START = 0;
constexpr size_t OFF_SUB1  = 64;
constexpr size_t OFF_SUB2  = 128;
constexpr size_t OFF_IDX   = 256;      // int idx[8][2048]
constexpr size_t OFF_V1    = 66048;    // uint v1[8][8192]
constexpr size_t OFF_KNN   = 328448;   // int knn[8][2048][16]
constexpr size_t OFF_XT    = 1377280;  // float xT[8][8192][64]

struct TF { unsigned a, b; };

__device__ __forceinline__ TF tf2(unsigned k0, unsigned k1, unsigned c0, unsigned c1) {
  unsigned ks2 = k0 ^ k1 ^ 0x1BD11BDAu;
  unsigned x0 = c0 + k0;
  unsigned x1 = c1 + k1;
#define TF_R(r) { x0 += x1; x1 = (x1 << r) | (x1 >> (32 - r)); x1 ^= x0; }
  TF_R(13) TF_R(15) TF_R(26) TF_R(6)
  x0 += k1;  x1 += ks2 + 1u;
  TF_R(17) TF_R(29) TF_R(16) TF_R(24)
  x0 += ks2; x1 += k0 + 2u;
  TF_R(13) TF_R(15) TF_R(26) TF_R(6)
  x0 += k0;  x1 += k1 + 3u;
  TF_R(17) TF_R(29) TF_R(16) TF_R(24)
  x0 += k1;  x1 += ks2 + 4u;
  TF_R(13) TF_R(15) TF_R(26) TF_R(6)
  x0 += ks2; x1 += k0 + 5u;
#undef TF_R
  TF r; r.a = x0; r.b = x1; return r;
}

// ---------------- PRNG setup (jax_threefry_partitionable=True, verified R1) ----------------
__global__ void rng_setup(unsigned* __restrict__ startB,
                          unsigned* __restrict__ sub1,
                          unsigned* __restrict__ sub2) {
  if (threadIdx.x != 0) return;
  const unsigned K0 = 0u, K1 = 42u; // jax.random.key(42)
  for (int b = 0; b < NB; ++b) {
    TF kb = tf2(K0, K1, 0u, (unsigned)b);
    TF k2 = tf2(kb.a, kb.b, 0u, 1u);
    TF bt = tf2(k2.a, k2.b, 0u, 0u);
    startB[b] = (bt.a ^ bt.b) & (unsigned)(NN - 1);
  }
  TF keyr = tf2(K0, K1, 0u, 1u); // fold_in(key42, 1)
  for (int b = 0; b < NB; ++b) {
    TF rk = tf2(keyr.a, keyr.b, 0u, (unsigned)b);   // rkeys[b]
    TF s1 = tf2(rk.a, rk.b, 0u, 1u);                // round-1 subkey
    TF nk = tf2(rk.a, rk.b, 0u, 0u);                // round-1 carried key
    TF s2 = tf2(nk.a, nk.b, 0u, 1u);                // round-2 subkey
    sub1[2*b] = s1.a; sub1[2*b+1] = s1.b;
    sub2[2*b] = s2.a; sub2[2*b+1] = s2.b;
  }
}

// ---- DPP wave64 reductions (VALU-only). Verified pattern R4-R6. ----
__device__ __forceinline__ float wave_max_dpp(float v) {
  int vi;
  vi = __builtin_amdgcn_update_dpp(__float_as_int(v), __float_as_int(v), 0x111, 0xf, 0xf, false);
  v = fmaxf(v, __int_as_float(vi));
  vi = __builtin_amdgcn_update_dpp(__float_as_int(v), __float_as_int(v), 0x112, 0xf, 0xf, false);
  v = fmaxf(v, __int_as_float(vi));
  vi = __builtin_amdgcn_update_dpp(__float_as_int(v), __float_as_int(v), 0x114, 0xf, 0xf, false);
  v = fmaxf(v, __int_as_float(vi));
  vi = __builtin_amdgcn_update_dpp(__float_as_int(v), __float_as_int(v), 0x118, 0xf, 0xf, false);
  v = fmaxf(v, __int_as_float(vi));
  vi = __builtin_amdgcn_update_dpp(__float_as_int(v), __float_as_int(v), 0x142, 0xa, 0xf, false);
  v = fmaxf(v, __int_as_float(vi));
  vi = __builtin_amdgcn_update_dpp(__float_as_int(v), __float_as_int(v), 0x143, 0xc, 0xf, false);
  v = fmaxf(v, __int_as_float(vi));
  return __int_as_float(__builtin_amdgcn_readlane(__float_as_int(v), 63));
}
__device__ __forceinline__ float wave_min_dpp(float v) {
  int vi;
  vi = __builtin_amdgcn_update_dpp(__float_as_int(v), __float_as_int(v), 0x111, 0xf, 0xf, false);
  v = fminf(v, __int_as_float(vi));
  vi = __builtin_amdgcn_update_dpp(__float_as_int(v), __float_as_int(v), 0x112, 0xf, 0xf, false);
  v = fminf(v, __int_as_float(vi));
  vi = __builtin_amdgcn_update_dpp(__float_as_int(v), __float_as_int(v), 0x114, 0xf, 0xf, false);
  v = fminf(v, __int_as_float(vi));
  vi = __builtin_amdgcn_update_dpp(__float_as_int(v), __float_as_int(v), 0x118, 0xf, 0xf, false);
  v = fminf(v, __int_as_float(vi));
  vi = __builtin_amdgcn_update_dpp(__float_as_int(v), __float_as_int(v), 0x142, 0xa, 0xf, false);
  v = fminf(v, __int_as_float(vi));
  vi = __builtin_amdgcn_update_dpp(__float_as_int(v), __float_as_int(v), 0x143, 0xc, 0xf, false);
  v = fminf(v, __int_as_float(vi));
  return __int_as_float(__builtin_amdgcn_readlane(__float_as_int(v), 63));
}
// one lexicographic u64 max DPP step; ctrl/rmask are template constants
// (builtin requires compile-time integer args — R7 compile fix)
template<int CTRL, int RMASK>
__device__ __forceinline__ unsigned long long dpp_pmax(unsigned long long v) {
  unsigned hi = (unsigned)(v >> 32), lo = (unsigned)v;
  unsigned h2 = (unsigned)__builtin_amdgcn_update_dpp((int)hi, (int)hi, CTRL, RMASK, 0xf, false);
  unsigned l2 = (unsigned)__builtin_amdgcn_update_dpp((int)lo, (int)lo, CTRL, RMASK, 0xf, false);
  unsigned long long o = ((unsigned long long)h2 << 32) | l2;
  return o > v ? o : v;
}
__device__ __forceinline__ unsigned long long readlane_u64(unsigned long long v, int l) {
  unsigned hi = (unsigned)__builtin_amdgcn_readlane((int)(v >> 32), l);
  unsigned lo = (unsigned)__builtin_amdgcn_readlane((int)(v & 0xffffffffu), l);
  return ((unsigned long long)hi << 32) | lo;
}

__device__ __forceinline__ unsigned mexp10(unsigned v) { // expand 10 bits, stride 3
  v &= 1023u;
  v = (v | (v << 16)) & 0x030000FFu;
  v = (v | (v << 8))  & 0x0300F00Fu;
  v = (v | (v << 4))  & 0x030C30C3u;
  v = (v | (v << 2))  & 0x09249249u;
  return v;
}

template<int TS>
__device__ void bitonic8192_t(unsigned long long* s, int tid) {
  for (unsigned k = 2; k <= 8192u; k <<= 1) {
    for (unsigned j = k >> 1; j > 0; j >>= 1) {
      __syncthreads();
      for (unsigned t = (unsigned)tid; t < 4096u; t += (unsigned)TS) {
        unsigned i = ((t & ~(j - 1u)) << 1) | (t & (j - 1u));
        unsigned p = i | j;
        bool up = ((i & k) == 0u);
        unsigned long long a = s[i], c = s[p];
        if ((a > c) == up) { s[i] = c; s[p] = a; }
      }
    }
  }
  __syncthreads();
}

// ---------------- FPS: Morton-bucketed exact pruning ----------------
// One block (512 thr, 8 waves) per batch. Points Morton-sorted into 128
// buckets x 64 pts (coords+dist+orig in LDS). Per iter, bucket skipped
// exactly when minBoxDist2(c) >= bucketMax*1.0002 (margin >> 4e-7 rounding
// => every d(p,c) > dist[p], update provably no-op, cached argmax key valid).
// Argmax keys u64 (distbits<<26 | (8191-orig)<<13 | sortedpos): max => max
// dist, tie => smallest original index (exact jnp.argmax semantics).
// Wave w owns buckets {8l+w}; metadata stored swizzled at (w<<4)|l so the
// 16-lane check reads are LDS-contiguous (conflict-free).
__global__ __launch_bounds__(512, 2) void fps_kernel(const float* __restrict__ pos,
                                                     const unsigned* __restrict__ startB,
                                                     int* __restrict__ idx) {
  __shared__ __align__(16) char smem[152704];
  float*              SX   = (float*)(smem);                    // [0,32K)
  float*              SY   = (float*)(smem + 32768);            // [32K,64K)
  float*              SZ   = (float*)(smem + 65536);            // [64K,96K)
  float*              DIST = (float*)(smem + 98304);            // [96K,128K)
  unsigned short*     ORIG = (unsigned short*)(smem + 131072);  // [128K,144K)
  float4*             BBLO = (float4*)(smem + 147456);          // [144K,146K)
  float4*             BBHI = (float4*)(smem + 149504);          // [146K,148K)
  unsigned long long* KEYS = (unsigned long long*)(smem + 151552); // 1KB
  unsigned long long* SLOT = (unsigned long long*)(smem + 152576); // 2x8
  unsigned long long* SORT = (unsigned long long*)(smem + 32768);  // alias SY/SZ
  const int b = blockIdx.x;
  const int tid = threadIdx.x;
  const int wv = tid >> 6, lane = tid & 63;
  const float* pb = pos + (size_t)b * 3 * NN;

  // --- phase 1: morton keys ---
  {
    const int j0 = tid * 16;
    const float4* f4x = (const float4*)(pb + j0);
    const float4* f4y = (const float4*)(pb + NN + j0);
    const float4* f4z = (const float4*)(pb + 2 * NN + j0);
#pragma unroll
    for (int q = 0; q < 4; ++q) {
      float4 a = f4x[q], c = f4y[q], e = f4z[q];
      float xs[4] = {a.x, a.y, a.z, a.w};
      float ys[4] = {c.x, c.y, c.z, c.w};
      float zs[4] = {e.x, e.y, e.z, e.w};
#pragma unroll
      for (int r = 0; r < 4; ++r) {
        int cx = (int)((xs[r] + 8.0f) * 64.0f); cx = cx < 0 ? 0 : (cx > 1023 ? 1023 : cx);
        int cy = (int)((ys[r] + 8.0f) * 64.0f); cy = cy < 0 ? 0 : (cy > 1023 ? 1023 : cy);
        int cz = (int)((zs[r] + 8.0f) * 64.0f); cz = cz < 0 ? 0 : (cz > 1023 ? 1023 : cz);
        unsigned key = mexp10((unsigned)cx) | (mexp10((unsigned)cy) << 1) | (mexp10((unsigned)cz) << 2);
        int j = j0 + 4 * q + r;
        SORT[j] = ((unsigned long long)key << 13) | (unsigned)j;
      }
    }
  }
  bitonic8192_t<512>(SORT, tid);
  // --- phase 2: gather into sorted order (SORT aliases SY/SZ: regs+barrier) ---
  unsigned long long sv[16];
#pragma unroll
  for (int t = 0; t < 16; ++t) sv[t] = SORT[tid * 16 + t];
  __syncthreads();
#pragma unroll
  for (int t = 0; t < 16; ++t) {
    int j = tid * 16 + t;
    int i = (int)(sv[t] & 8191u);
    SX[j] = pb[i]; SY[j] = pb[NN + i]; SZ[j] = pb[2 * NN + i];
    ORIG[j] = (unsigned short)i;
    DIST[j] = 1e10f;
  }
  __syncthreads();
  // --- phase 3: per-bucket AABB + init keys (force-active: dist=1e10) ---
  for (int m = 0; m < 16; ++m) {
    int bu = (m << 3) + wv;               // bucket id
    int p = (bu << 6) + lane;
    float x = SX[p], y = SY[p], z = SZ[p];
    float xmn = wave_min_dpp(x), xmx = wave_max_dpp(x);
    float ymn = wave_min_dpp(y), ymx = wave_max_dpp(y);
    float zmn = wave_min_dpp(z), zmx = wave_max_dpp(z);
    if (lane == 0) {
      int meta = (wv << 4) | m;
      BBLO[meta] = make_float4(xmn, ymn, zmn, 0.f);
      BBHI[meta] = make_float4(xmx, ymx, zmx, 0.f);
      KEYS[meta] = ((unsigned long long)0x501502F9u << 26); // bits(1e10)
    }
  }
  int widx = (int)startB[b];
  float cx = pb[widx], cy = pb[NN + widx], cz = pb[2 * NN + widx];
  if (tid == 0) idx[b * NM] = widx;
  __syncthreads();
  // --- main loop: 1432 serial steps ---
  for (int it = 1; it < NFPS; ++it) {
    const int par = it & 1;
    const int l = lane & 15;
    const int meta = (wv << 4) | l;
    unsigned long long kreg = KEYS[meta];
    float4 blo = BBLO[meta], bhi = BBHI[meta];
    float bmax = __uint_as_float((unsigned)(kreg >> 26));
    float dxm = fmaxf(fmaxf(blo.x - cx, cx - bhi.x), 0.f);
    float dym = fmaxf(fmaxf(blo.y - cy, cy - bhi.y), 0.f);
    float dzm = fmaxf(fmaxf(blo.z - cz, cz - bhi.z), 0.f);
    float minb2 = dxm * dxm + dym * dym + dzm * dzm;
    bool act = (lane < 16) && (minb2 < bmax * 1.0002f);
    unsigned long long mask = __ballot(act);
    while (mask) {
      const int ls = (int)__builtin_ctzll(mask); mask &= mask - 1;
      const int bu = (ls << 3) + wv;
      const int p = (bu << 6) + lane;
      float x = SX[p], y = SY[p], z = SZ[p];
      float dold = DIST[p];
      unsigned o = ORIG[p];
      // Mirror numpy/XLA exactly: rn ops, no FMA, ((dx2+dy2)+dz2)
      float dx = __fsub_rn(x, cx);
      float dy = __fsub_rn(y, cy);
      float dz = __fsub_rn(z, cz);
      float d  = __fadd_rn(__fadd_rn(__fmul_rn(dx, dx), __fmul_rn(dy, dy)),
                           __fmul_rn(dz, dz));
      float nd = fminf(dold, d);
      DIST[p] = nd;
      unsigned ndb = __float_as_uint(nd);
      unsigned long long v = ((unsigned long long)ndb << 26)
                           | ((unsigned long long)(8191u - o) << 13)
                           | (unsigned)p;
      v = dpp_pmax<0x111, 0xf>(v);
      v = dpp_pmax<0x112, 0xf>(v);
      v = dpp_pmax<0x114, 0xf>(v);
      v = dpp_pmax<0x118, 0xf>(v);
      v = dpp_pmax<0x142, 0xa>(v);
      v = dpp_pmax<0x143, 0xc>(v);
      unsigned long long nk = readlane_u64(v, 63);
      if (lane == 0) KEYS[(wv << 4) | ls] = nk;
      kreg = (lane == ls) ? nk : kreg;
    }
    // per-wave candidate: max over lanes 0..15 of kreg
    unsigned long long cnd = (lane < 16) ? kreg : 0ull;
    cnd = dpp_pmax<0x111, 0xf>(cnd);
    cnd = dpp_pmax<0x112, 0xf>(cnd);
    cnd = dpp_pmax<0x114, 0xf>(cnd);
    cnd = dpp_pmax<0x118, 0xf>(cnd);
    cnd = readlane_u64(cnd, 15);
    if (lane == 0) SLOT[par * 8 + wv] = cnd;
    __syncthreads();
    unsigned long long k0 = SLOT[par * 8 + 0], k1 = SLOT[par * 8 + 1];
    unsigned long long k2 = SLOT[par * 8 + 2], k3 = SLOT[par * 8 + 3];
    unsigned long long k4 = SLOT[par * 8 + 4], k5 = SLOT[par * 8 + 5];
    unsigned long long k6 = SLOT[par * 8 + 6], k7 = SLOT[par * 8 + 7];
    if (k1 > k0) k0 = k1;
    if (k3 > k2) k2 = k3;
    if (k5 > k4) k4 = k5;
    if (k7 > k6) k6 = k7;
    if (k2 > k0) k0 = k2;
    if (k6 > k4) k4 = k6;
    if (k4 > k0) k0 = k4;
    const int js = (int)(k0 & 8191u);                  // sorted position
    const int oo = 8191 - (int)((k0 >> 13) & 8191u);   // original index
    cx = SX[js]; cy = SY[js]; cz = SZ[js];             // broadcast reads
    if (tid == 0) idx[b * NM + it] = oo;
  }
}

// ---------------- permutation: 2 independent stable sorts, 16 blocks ----------------
// block = (batch, round). Round 0 writes the full round-1 permutation v1;
// round 1 writes its first NRAND payload positions into idx (composed later).
__global__ __launch_bounds__(1024) void perm_kernel(const unsigned* __restrict__ sub1,
                                                    const unsigned* __restrict__ sub2,
                                                    unsigned* __restrict__ v1buf,
                                                    int* __restrict__ idx) {
  __shared__ unsigned long long s[NN]; // 64 KB
  const int bl = blockIdx.x;
  const int b = bl >> 1, r = bl & 1;
  const int tid = threadIdx.x;
  const unsigned* sk = (r == 0) ? sub1 : sub2;
  const unsigned ka = sk[2*b], kb = sk[2*b+1];
  for (int i = tid; i < NN; i += 1024) {
    TF t = tf2(ka, kb, 0u, (unsigned)i);
    // composite (key<<32)|position => stable sort incl. key collisions
    s[i] = ((unsigned long long)(t.a ^ t.b) << 32) | (unsigned)i;
  }
  bitonic8192_t<1024>(s, tid);
  if (r == 0) {
    unsigned* v1 = v1buf + (size_t)b * NN;
    for (int i = tid; i < NN; i += 1024) v1[i] = (unsigned)(s[i] & 0xffffffffu);
  } else {
    for (int t = tid; t < NRAND; t += 1024)
      idx[b * NM + NFPS + t] = (int)(s[t] & 0xffffffffu);
  }
}

// ---------------- pos_sub gather (composes v1[v2] for the random part) ----------------
__global__ void possub_kernel(const float* __restrict__ pos,
                              const int* __restrict__ idx,
                              const unsigned* __restrict__ v1,
                              float* __restrict__ posOut) {
  int i = blockIdx.x * 256 + threadIdx.x;
  if (i >= NB * 3 * NM) return;
  int mm = i & (NM - 1);
  int bd = i >> 11;            // b*3 + d
  int d = bd % 3, b = bd / 3;
  int raw = idx[b * NM + mm];
  int id = (mm < NFPS) ? raw : (int)v1[(size_t)b * NN + raw];
  posOut[i] = pos[((size_t)b * 3 + d) * NN + id];
}

// ---------------- transpose x [B,C,N] -> xT [B,N,C] ----------------
__global__ void transpose_kernel(const float* __restrict__ x, float* __restrict__ xT) {
  __shared__ float t[32][33];
  int b = blockIdx.z;
  int n0 = blockIdx.x * 32, c0 = blockIdx.y * 32;
  int tx = threadIdx.x, ty = threadIdx.y;
  t[ty][tx] = x[((size_t)b * NC + (c0 + ty)) * NN + n0 + tx];
  __syncthreads();
  xT[((size_t)b * NN + (n0 + ty)) * NC + c0 + tx] = t[tx][ty];
}

// ---------------- KNN: one wave per sampled point ----------------
// Per-lane top-16 in registers (branchless v_med3 chain); LDS only for the
// final 64-list wave merge (verified R3).
__global__ __launch_bounds__(256) void knn_kernel(const float* __restrict__ pos,
                                                  const float* __restrict__ posSub,
                                                  int* __restrict__ knn) {
  __shared__ unsigned long long lst[4][NK][64]; // [wave][rank][lane], 32 KB
  const int tid = threadIdx.x;
  const int wv = tid >> 6, lane = tid & 63;
  const int g = blockIdx.x * 4 + wv;            // 0..16383
  const int b = g >> 11, mm = g & (NM - 1);
  const float* pb = pos + (size_t)b * 3 * NN;
  const float* ps = posSub + (size_t)b * 3 * NM;
  const float sx = ps[mm], sy = ps[NM + mm], sz = ps[2 * NM + mm];
  const float sm = __fadd_rn(__fadd_rn(__fmul_rn(sx, sx), __fmul_rn(sy, sy)),
                             __fmul_rn(sz, sz));
  float key[NK]; int kid[NK];
#pragma unroll
  for (int i = 0; i < NK; ++i) { key[i] = __int_as_float(0x7F800000); kid[i] = 0; }
  for (int t = 0; t < NN / 64; ++t) {
    const int n = t * 64 + lane;
    float x = pb[n], y = pb[NN + n], z = pb[2 * NN + n];
    float sn = __fadd_rn(__fadd_rn(__fmul_rn(x, x), __fmul_rn(y, y)), __fmul_rn(z, z));
    float dt = __fadd_rn(__fadd_rn(__fmul_rn(sx, x), __fmul_rn(sy, y)), __fmul_rn(sz, z));
    float d2 = __fsub_rn(__fadd_rn(sm, sn), __fmul_rn(2.0f, dt)); // mirror reference
    const float ck = d2; const int ci = n;
#pragma unroll
    for (int i = NK - 1; i >= 1; --i) {
      float lo = key[i-1], hi = key[i];
      bool cLo = ck < lo, cHi = ck < hi;
      key[i] = __builtin_amdgcn_fmed3f(ck, lo, hi);
      kid[i] = cLo ? kid[i-1] : (cHi ? ci : kid[i]);
    }
    bool c0 = ck < key[0];
    kid[0] = c0 ? ci : kid[0];
    key[0] = fminf(key[0], ck);
  }
#pragma unroll
  for (int i = 0; i < NK; ++i) {
    unsigned u = __float_as_uint(key[i]);
    u = (u & 0x80000000u) ? ~u : (u | 0x80000000u);
    lst[wv][i][lane] = ((unsigned long long)u << 32) | (unsigned)kid[i];
  }
  int ptr = 0;
  unsigned long long head = lst[wv][0][lane];
  unsigned myn = 0;
  for (int k = 0; k < NK; ++k) {
    unsigned long long mn = head;
#pragma unroll
    for (int off = 32; off > 0; off >>= 1) {
      unsigned long long o = __shfl_xor(mn, off, 64);
      if (o < mn) mn = o;
    }
    if (head == mn) { ++ptr; head = (ptr < NK) ? lst[wv][ptr][lane] : ~0ull; }
    if (lane == k) myn = (unsigned)(mn & 0xffffffffu);
  }
  if (lane < NK) knn[(size_t)g * NK + lane] = (int)myn;
}

// ---------------- weights + gather + weighted sum ----------------
__global__ __launch_bounds__(256) void final_kernel(const float* __restrict__ xT,
                                                    const float* __restrict__ pos,
                                                    const float* __restrict__ posSub,
                                                    const int* __restrict__ knn,
                                                    float* __restrict__ xOut) {
  __shared__ float tile[64][17];
  const int tid = threadIdx.x;
  const int wv = tid >> 6, lane = tid & 63;
  const int base = blockIdx.x * 16;      // 16 consecutive samples, same batch
  const int b = base >> 11;
  const float* pb = pos + (size_t)b * 3 * NN;
  const float* ps = posSub + (size_t)b * 3 * NM;
  for (int j = 0; j < 4; ++j) {
    const int ml = wv * 4 + j;           // 0..15
    const int g = base + ml;
    const int mm = g & (NM - 1);
    const float sx = ps[mm], sy = ps[NM + mm], sz = ps[2 * NM + mm];
    const int kk = lane & 15;
    const int nk = knn[(size_t)g * NK + kk];
    float dx = __fsub_rn(pb[nk], sx);
    float dy = __fsub_rn(pb[NN + nk], sy);
    float dz = __fsub_rn(pb[2 * NN + nk], sz);
    float dd = __fadd_rn(__fadd_rn(__fmul_rn(dx, dx), __fmul_rn(dy, dy)),
                         __fmul_rn(dz, dz));
    float d = __fsqrt_rn(dd);
    d = fmaxf(d, 1e-6f);
    float e = __fdiv_rn(0.0f - d, 0.2f);
    float mx = e;
#pragma unroll
    for (int off = 8; off > 0; off >>= 1) mx = fmaxf(mx, __shfl_xor(mx, off, 16));
    float ex = expf(__fsub_rn(e, mx));
    float sum = ex;
#pragma unroll
    for (int off = 8; off > 0; off >>= 1) sum = __fadd_rn(sum, __shfl_xor(sum, off, 16));
    float wgt = __fdiv_rn(ex, sum);
    float acc = 0.0f;
#pragma unroll
    for (int k = 0; k < NK; ++k) {
      float wk = __shfl(wgt, k, 64);
      int   nn = __shfl(nk, k, 64);
      acc = __fadd_rn(acc, __fmul_rn(wk, xT[((size_t)b * NN + nn) * NC + lane]));
    }
    tile[lane][ml] = acc;
  }
  __syncthreads();
  const int m0 = base & (NM - 1);
  for (int e2 = tid; e2 < 64 * 16; e2 += 256) {
    int c = e2 >> 4, ml = e2 & 15;
    xOut[((size_t)b * NC + c) * NM + m0 + ml] = tile[c][ml];
  }
}

extern "C" void kernel_launch(void* const* d_in, const int* in_sizes, int n_in,
                              void* d_out, int out_size, void* d_ws, size_t ws_size,
                              hipStream_t stream) {
  const float* x   = (const float*)d_in[0];
  const float* pos = (const float*)d_in[1];
  float* xOut   = (float*)d_out;
  float* posOut = xOut + (size_t)NB * NC * NM;

  char* w = (char*)d_ws;
  unsigned* startB = (unsigned*)(w + OFF_START);
  unsigned* sub1   = (unsigned*)(w + OFF_SUB1);
  unsigned* sub2   = (unsigned*)(w + OFF_SUB2);
  int*      idx    = (int*)(w + OFF_IDX);
  unsigned* v1     = (unsigned*)(w + OFF_V1);
  int*      knn    = (int*)(w + OFF_KNN);
  float*    xT     = (float*)(w + OFF_XT);

  hipLaunchKernelGGL(rng_setup, dim3(1), dim3(64), 0, stream, startB, sub1, sub2);
  hipLaunchKernelGGL(fps_kernel, dim3(NB), dim3(512), 0, stream, pos, startB, idx);
  hipLaunchKernelGGL(perm_kernel, dim3(2 * NB), dim3(1024), 0, stream, sub1, sub2, v1, idx);
  hipLaunchKernelGGL(possub_kernel, dim3((NB * 3 * NM + 255) / 256), dim3(256), 0, stream,
                     pos, idx, v1, posOut);
  hipLaunchKernelGGL(transpose_kernel, dim3(NN / 32, NC / 32, NB), dim3(32, 32), 0, stream,
                     x, xT);
  hipLaunchKernelGGL(knn_kernel, dim3(NB * NM / 4), dim3(256), 0, stream, pos, posOut, knn);
  hipLaunchKernelGGL(final_kernel, dim3(NB * NM / 16), dim3(256), 0, stream,
                     xT, pos, posOut, knn, xOut);
}

// Round 9
// 2907.000 us; speedup vs baseline: 1.0855x; 1.0855x over previous
//
#include <hip/hip_runtime.h>

// Problem constants (match reference)
constexpr int NB   = 8;     // batches
constexpr int NC   = 64;    // channels
constexpr int NN   = 8192;  // points
constexpr int NM   = 2048;  // samples
constexpr int NK   = 16;    // knn
constexpr int NFPS = 1433;  // int(2048*0.7)
constexpr int NRAND = NM - NFPS; // 615

// ---------------- workspace layout (bytes) ----------------
constexpr size_t OFF_START = 0;
constexpr size_t OFF_SUB1  = 64;
constexpr size_t OFF_SUB2  = 128;
constexpr size_t OFF_IDX   = 256;      // int idx[8][2048]
constexpr size_t OFF_V1    = 66048;    // uint v1[8][8192]
constexpr size_t OFF_KNN   = 328448;   // int knn[8][2048][16]
constexpr size_t OFF_XT    = 1377280;  // float xT[8][8192][64]

struct TF { unsigned a, b; };

__device__ __forceinline__ TF tf2(unsigned k0, unsigned k1, unsigned c0, unsigned c1) {
  unsigned ks2 = k0 ^ k1 ^ 0x1BD11BDAu;
  unsigned x0 = c0 + k0;
  unsigned x1 = c1 + k1;
#define TF_R(r) { x0 += x1; x1 = (x1 << r) | (x1 >> (32 - r)); x1 ^= x0; }
  TF_R(13) TF_R(15) TF_R(26) TF_R(6)
  x0 += k1;  x1 += ks2 + 1u;
  TF_R(17) TF_R(29) TF_R(16) TF_R(24)
  x0 += ks2; x1 += k0 + 2u;
  TF_R(13) TF_R(15) TF_R(26) TF_R(6)
  x0 += k0;  x1 += k1 + 3u;
  TF_R(17) TF_R(29) TF_R(16) TF_R(24)
  x0 += k1;  x1 += ks2 + 4u;
  TF_R(13) TF_R(15) TF_R(26) TF_R(6)
  x0 += ks2; x1 += k0 + 5u;
#undef TF_R
  TF r; r.a = x0; r.b = x1; return r;
}

// ---------------- PRNG setup (jax_threefry_partitionable=True, verified R1) ----------------
__global__ void rng_setup(unsigned* __restrict__ startB,
                          unsigned* __restrict__ sub1,
                          unsigned* __restrict__ sub2) {
  if (threadIdx.x != 0) return;
  const unsigned K0 = 0u, K1 = 42u; // jax.random.key(42)
  for (int b = 0; b < NB; ++b) {
    TF kb = tf2(K0, K1, 0u, (unsigned)b);
    TF k2 = tf2(kb.a, kb.b, 0u, 1u);
    TF bt = tf2(k2.a, k2.b, 0u, 0u);
    startB[b] = (bt.a ^ bt.b) & (unsigned)(NN - 1);
  }
  TF keyr = tf2(K0, K1, 0u, 1u); // fold_in(key42, 1)
  for (int b = 0; b < NB; ++b) {
    TF rk = tf2(keyr.a, keyr.b, 0u, (unsigned)b);   // rkeys[b]
    TF s1 = tf2(rk.a, rk.b, 0u, 1u);                // round-1 subkey
    TF nk = tf2(rk.a, rk.b, 0u, 0u);                // round-1 carried key
    TF s2 = tf2(nk.a, nk.b, 0u, 1u);                // round-2 subkey
    sub1[2*b] = s1.a; sub1[2*b+1] = s1.b;
    sub2[2*b] = s2.a; sub2[2*b+1] = s2.b;
  }
}

// one lexicographic u64 max DPP step; ctrl/rmask template constants (R8-verified)
template<int CTRL, int RMASK>
__device__ __forceinline__ unsigned long long dpp_pmax(unsigned long long v) {
  unsigned hi = (unsigned)(v >> 32), lo = (unsigned)v;
  unsigned h2 = (unsigned)__builtin_amdgcn_update_dpp((int)hi, (int)hi, CTRL, RMASK, 0xf, false);
  unsigned l2 = (unsigned)__builtin_amdgcn_update_dpp((int)lo, (int)lo, CTRL, RMASK, 0xf, false);
  unsigned long long o = ((unsigned long long)h2 << 32) | l2;
  return o > v ? o : v;
}
__device__ __forceinline__ unsigned long long readlane_u64(unsigned long long v, int l) {
  unsigned hi = (unsigned)__builtin_amdgcn_readlane((int)(v >> 32), l);
  unsigned lo = (unsigned)__builtin_amdgcn_readlane((int)(v & 0xffffffffu), l);
  return ((unsigned long long)hi << 32) | lo;
}

__device__ __forceinline__ unsigned mexp10(unsigned v) { // expand 10 bits, stride 3
  v &= 1023u;
  v = (v | (v << 16)) & 0x030000FFu;
  v = (v | (v << 8))  & 0x0300F00Fu;
  v = (v | (v << 4))  & 0x030C30C3u;
  v = (v | (v << 2))  & 0x09249249u;
  return v;
}

template<int TS>
__device__ void bitonic8192_t(unsigned long long* s, int tid) {
  for (unsigned k = 2; k <= 8192u; k <<= 1) {
    for (unsigned j = k >> 1; j > 0; j >>= 1) {
      __syncthreads();
      for (unsigned t = (unsigned)tid; t < 4096u; t += (unsigned)TS) {
        unsigned i = ((t & ~(j - 1u)) << 1) | (t & (j - 1u));
        unsigned p = i | j;
        bool up = ((i & k) == 0u);
        unsigned long long a = s[i], c = s[p];
        if ((a > c) == up) { s[i] = c; s[p] = a; }
      }
    }
  }
  __syncthreads();
}

// ---------------- FPS: per-THREAD Morton-region pruning ----------------
// One block (512 thr, 8 waves) per batch. Points Morton-sorted; thread tid
// logically owns 16 contiguous sorted points j=tid*16+t, stored at phys slot
// t*512+tid as float4(x,y,z,origbits) => sweep reads are contiguous b128
// (conflict-free) and the per-thread AABB is spatially tight. dist[16] and
// the cached best key live in REGISTERS. Per iter: ~12-op skip test
// (minBoxDist2 >= myMax*1.0002, fp-safe margin, R8-verified); threads that
// skip keep their cached key; waves with zero active lanes branch over the
// whole sweep. Global argmax: full-wave u64 DPP max (R8-verified) + 8-slot
// merge + ONE barrier. Key = distbits<<26 | (8191-orig)<<13 | phys: max =>
// max dist, tie => smallest orig index (exact jnp.argmax semantics).
__global__ __launch_bounds__(512, 1) void fps_kernel(const float* __restrict__ pos,
                                                     const unsigned* __restrict__ startB,
                                                     int* __restrict__ idx) {
  __shared__ __align__(16) char smem[131072 + 128];
  float4*             PTS  = (float4*)smem;                       // 128 KB
  unsigned long long* SORT = (unsigned long long*)smem;           // alias, 64 KB
  unsigned long long* SLOT = (unsigned long long*)(smem + 131072);// [2][8]
  const int b = blockIdx.x;
  const int tid = threadIdx.x;
  const int wv = tid >> 6, lane = tid & 63;
  const float* pb = pos + (size_t)b * 3 * NN;

  // --- phase 1: morton keys ---
  {
    const int j0 = tid * 16;
    const float4* f4x = (const float4*)(pb + j0);
    const float4* f4y = (const float4*)(pb + NN + j0);
    const float4* f4z = (const float4*)(pb + 2 * NN + j0);
#pragma unroll
    for (int q = 0; q < 4; ++q) {
      float4 a = f4x[q], c = f4y[q], e = f4z[q];
      float xs[4] = {a.x, a.y, a.z, a.w};
      float ys[4] = {c.x, c.y, c.z, c.w};
      float zs[4] = {e.x, e.y, e.z, e.w};
#pragma unroll
      for (int r = 0; r < 4; ++r) {
        int cx = (int)((xs[r] + 8.0f) * 64.0f); cx = cx < 0 ? 0 : (cx > 1023 ? 1023 : cx);
        int cy = (int)((ys[r] + 8.0f) * 64.0f); cy = cy < 0 ? 0 : (cy > 1023 ? 1023 : cy);
        int cz = (int)((zs[r] + 8.0f) * 64.0f); cz = cz < 0 ? 0 : (cz > 1023 ? 1023 : cz);
        unsigned key = mexp10((unsigned)cx) | (mexp10((unsigned)cy) << 1) | (mexp10((unsigned)cz) << 2);
        int j = j0 + 4 * q + r;
        SORT[j] = ((unsigned long long)key << 13) | (unsigned)j;
      }
    }
  }
  bitonic8192_t<512>(SORT, tid);
  // --- phase 2: scatter into phys layout (SORT aliases PTS: regs + barrier) ---
  unsigned long long sv[16];
#pragma unroll
  for (int t = 0; t < 16; ++t) sv[t] = SORT[tid * 16 + t];
  __syncthreads();
#pragma unroll
  for (int t = 0; t < 16; ++t) {
    int i = (int)(sv[t] & 8191u);
    PTS[t * 512 + tid] = make_float4(pb[i], pb[NN + i], pb[2 * NN + i],
                                     __uint_as_float((unsigned)i));
  }
  __syncthreads();
  // --- phase 3: per-thread AABB + dist init ---
  float dist[16];
  float axn = 1e30f, ayn = 1e30f, azn = 1e30f;
  float axx = -1e30f, ayx = -1e30f, azx = -1e30f;
#pragma unroll
  for (int t = 0; t < 16; ++t) {
    float4 P = PTS[t * 512 + tid];
    axn = fminf(axn, P.x); axx = fmaxf(axx, P.x);
    ayn = fminf(ayn, P.y); ayx = fmaxf(ayx, P.y);
    azn = fminf(azn, P.z); azx = fmaxf(azx, P.z);
    dist[t] = 1e10f;
  }
  unsigned long long ckey = ((unsigned long long)0x501502F9u << 26); // dist=1e10
  int widx = (int)startB[b];
  float cx = pb[widx], cy = pb[NN + widx], cz = pb[2 * NN + widx];
  if (tid == 0) idx[b * NM] = widx;

  // --- main loop: 1432 serial steps, ONE barrier each ---
  for (int it = 1; it < NFPS; ++it) {
    const int par = it & 1;
    float bmax = __uint_as_float((unsigned)(ckey >> 26));
    float dxm = fmaxf(fmaxf(axn - cx, cx - axx), 0.f);
    float dym = fmaxf(fmaxf(ayn - cy, cy - ayx), 0.f);
    float dzm = fmaxf(fmaxf(azn - cz, cz - azx), 0.f);
    float minb2 = dxm * dxm + dym * dym + dzm * dzm;
    if (minb2 < bmax * 1.0002f) {            // active: full 16-slot sweep
      unsigned long long best = 0ull;
#pragma unroll
      for (int q = 0; q < 16; ++q) {
        float4 P = PTS[q * 512 + tid];       // b128, conflict-free
        // Mirror numpy/XLA exactly: rn ops, no FMA, ((dx2+dy2)+dz2)
        float dx = __fsub_rn(P.x, cx);
        float dy = __fsub_rn(P.y, cy);
        float dz = __fsub_rn(P.z, cz);
        float d  = __fadd_rn(__fadd_rn(__fmul_rn(dx, dx), __fmul_rn(dy, dy)),
                             __fmul_rn(dz, dz));
        float nd = fminf(dist[q], d);
        dist[q] = nd;
        unsigned o = __float_as_uint(P.w);
        unsigned long long k = ((unsigned long long)__float_as_uint(nd) << 26)
                             | ((unsigned long long)(8191u - o) << 13)
                             | (unsigned)(q * 512 + tid);
        if (k > best) best = k;
      }
      ckey = best;
    }
    // full-wave u64 max over cached keys
    unsigned long long v = ckey;
    v = dpp_pmax<0x111, 0xf>(v);
    v = dpp_pmax<0x112, 0xf>(v);
    v = dpp_pmax<0x114, 0xf>(v);
    v = dpp_pmax<0x118, 0xf>(v);
    v = dpp_pmax<0x142, 0xa>(v);
    v = dpp_pmax<0x143, 0xc>(v);
    unsigned long long wk = readlane_u64(v, 63);
    if (lane == 0) SLOT[par * 8 + wv] = wk;
    __syncthreads();
    unsigned long long k0 = SLOT[par * 8 + 0], k1 = SLOT[par * 8 + 1];
    unsigned long long k2 = SLOT[par * 8 + 2], k3 = SLOT[par * 8 + 3];
    unsigned long long k4 = SLOT[par * 8 + 4], k5 = SLOT[par * 8 + 5];
    unsigned long long k6 = SLOT[par * 8 + 6], k7 = SLOT[par * 8 + 7];
    if (k1 > k0) k0 = k1;
    if (k3 > k2) k2 = k3;
    if (k5 > k4) k4 = k5;
    if (k7 > k6) k6 = k7;
    if (k2 > k0) k0 = k2;
    if (k6 > k4) k4 = k6;
    if (k4 > k0) k0 = k4;
    const int phys = (int)(k0 & 8191u);
    float4 W = PTS[phys];                    // wave-uniform broadcast b128
    cx = W.x; cy = W.y; cz = W.z;
    if (tid == 0) idx[b * NM + it] = 8191 - (int)((k0 >> 13) & 8191u);
  }
}

// ---------------- permutation: 2 independent stable sorts, 16 blocks ----------------
// block = (batch, round). Round 0 writes the full round-1 permutation v1;
// round 1 writes its first NRAND payload positions into idx (composed later).
__global__ __launch_bounds__(1024) void perm_kernel(const unsigned* __restrict__ sub1,
                                                    const unsigned* __restrict__ sub2,
                                                    unsigned* __restrict__ v1buf,
                                                    int* __restrict__ idx) {
  __shared__ unsigned long long s[NN]; // 64 KB
  const int bl = blockIdx.x;
  const int b = bl >> 1, r = bl & 1;
  const int tid = threadIdx.x;
  const unsigned* sk = (r == 0) ? sub1 : sub2;
  const unsigned ka = sk[2*b], kb = sk[2*b+1];
  for (int i = tid; i < NN; i += 1024) {
    TF t = tf2(ka, kb, 0u, (unsigned)i);
    // composite (key<<32)|position => stable sort incl. key collisions
    s[i] = ((unsigned long long)(t.a ^ t.b) << 32) | (unsigned)i;
  }
  bitonic8192_t<1024>(s, tid);
  if (r == 0) {
    unsigned* v1 = v1buf + (size_t)b * NN;
    for (int i = tid; i < NN; i += 1024) v1[i] = (unsigned)(s[i] & 0xffffffffu);
  } else {
    for (int t = tid; t < NRAND; t += 1024)
      idx[b * NM + NFPS + t] = (int)(s[t] & 0xffffffffu);
  }
}

// ---------------- pos_sub gather (composes v1[v2] for the random part) ----------------
__global__ void possub_kernel(const float* __restrict__ pos,
                              const int* __restrict__ idx,
                              const unsigned* __restrict__ v1,
                              float* __restrict__ posOut) {
  int i = blockIdx.x * 256 + threadIdx.x;
  if (i >= NB * 3 * NM) return;
  int mm = i & (NM - 1);
  int bd = i >> 11;            // b*3 + d
  int d = bd % 3, b = bd / 3;
  int raw = idx[b * NM + mm];
  int id = (mm < NFPS) ? raw : (int)v1[(size_t)b * NN + raw];
  posOut[i] = pos[((size_t)b * 3 + d) * NN + id];
}

// ---------------- transpose x [B,C,N] -> xT [B,N,C] ----------------
__global__ void transpose_kernel(const float* __restrict__ x, float* __restrict__ xT) {
  __shared__ float t[32][33];
  int b = blockIdx.z;
  int n0 = blockIdx.x * 32, c0 = blockIdx.y * 32;
  int tx = threadIdx.x, ty = threadIdx.y;
  t[ty][tx] = x[((size_t)b * NC + (c0 + ty)) * NN + n0 + tx];
  __syncthreads();
  xT[((size_t)b * NN + (n0 + ty)) * NC + c0 + tx] = t[tx][ty];
}

// ---------------- KNN: one wave per sampled point ----------------
// Per-lane top-16 in registers (branchless v_med3 chain); LDS only for the
// final 64-list wave merge (verified R3).
__global__ __launch_bounds__(256) void knn_kernel(const float* __restrict__ pos,
                                                  const float* __restrict__ posSub,
                                                  int* __restrict__ knn) {
  __shared__ unsigned long long lst[4][NK][64]; // [wave][rank][lane], 32 KB
  const int tid = threadIdx.x;
  const int wv = tid >> 6, lane = tid & 63;
  const int g = blockIdx.x * 4 + wv;            // 0..16383
  const int b = g >> 11, mm = g & (NM - 1);
  const float* pb = pos + (size_t)b * 3 * NN;
  const float* ps = posSub + (size_t)b * 3 * NM;
  const float sx = ps[mm], sy = ps[NM + mm], sz = ps[2 * NM + mm];
  const float sm = __fadd_rn(__fadd_rn(__fmul_rn(sx, sx), __fmul_rn(sy, sy)),
                             __fmul_rn(sz, sz));
  float key[NK]; int kid[NK];
#pragma unroll
  for (int i = 0; i < NK; ++i) { key[i] = __int_as_float(0x7F800000); kid[i] = 0; }
  for (int t = 0; t < NN / 64; ++t) {
    const int n = t * 64 + lane;
    float x = pb[n], y = pb[NN + n], z = pb[2 * NN + n];
    float sn = __fadd_rn(__fadd_rn(__fmul_rn(x, x), __fmul_rn(y, y)), __fmul_rn(z, z));
    float dt = __fadd_rn(__fadd_rn(__fmul_rn(sx, x), __fmul_rn(sy, y)), __fmul_rn(sz, z));
    float d2 = __fsub_rn(__fadd_rn(sm, sn), __fmul_rn(2.0f, dt)); // mirror reference
    const float ck = d2; const int ci = n;
#pragma unroll
    for (int i = NK - 1; i >= 1; --i) {
      float lo = key[i-1], hi = key[i];
      bool cLo = ck < lo, cHi = ck < hi;
      key[i] = __builtin_amdgcn_fmed3f(ck, lo, hi);
      kid[i] = cLo ? kid[i-1] : (cHi ? ci : kid[i]);
    }
    bool c0 = ck < key[0];
    kid[0] = c0 ? ci : kid[0];
    key[0] = fminf(key[0], ck);
  }
#pragma unroll
  for (int i = 0; i < NK; ++i) {
    unsigned u = __float_as_uint(key[i]);
    u = (u & 0x80000000u) ? ~u : (u | 0x80000000u);
    lst[wv][i][lane] = ((unsigned long long)u << 32) | (unsigned)kid[i];
  }
  int ptr = 0;
  unsigned long long head = lst[wv][0][lane];
  unsigned myn = 0;
  for (int k = 0; k < NK; ++k) {
    unsigned long long mn = head;
#pragma unroll
    for (int off = 32; off > 0; off >>= 1) {
      unsigned long long o = __shfl_xor(mn, off, 64);
      if (o < mn) mn = o;
    }
    if (head == mn) { ++ptr; head = (ptr < NK) ? lst[wv][ptr][lane] : ~0ull; }
    if (lane == k) myn = (unsigned)(mn & 0xffffffffu);
  }
  if (lane < NK) knn[(size_t)g * NK + lane] = (int)myn;
}

// ---------------- weights + gather + weighted sum ----------------
__global__ __launch_bounds__(256) void final_kernel(const float* __restrict__ xT,
                                                    const float* __restrict__ pos,
                                                    const float* __restrict__ posSub,
                                                    const int* __restrict__ knn,
                                                    float* __restrict__ xOut) {
  __shared__ float tile[64][17];
  const int tid = threadIdx.x;
  const int wv = tid >> 6, lane = tid & 63;
  const int base = blockIdx.x * 16;      // 16 consecutive samples, same batch
  const int b = base >> 11;
  const float* pb = pos + (size_t)b * 3 * NN;
  const float* ps = posSub + (size_t)b * 3 * NM;
  for (int j = 0; j < 4; ++j) {
    const int ml = wv * 4 + j;           // 0..15
    const int g = base + ml;
    const int mm = g & (NM - 1);
    const float sx = ps[mm], sy = ps[NM + mm], sz = ps[2 * NM + mm];
    const int kk = lane & 15;
    const int nk = knn[(size_t)g * NK + kk];
    float dx = __fsub_rn(pb[nk], sx);
    float dy = __fsub_rn(pb[NN + nk], sy);
    float dz = __fsub_rn(pb[2 * NN + nk], sz);
    float dd = __fadd_rn(__fadd_rn(__fmul_rn(dx, dx), __fmul_rn(dy, dy)),
                         __fmul_rn(dz, dz));
    float d = __fsqrt_rn(dd);
    d = fmaxf(d, 1e-6f);
    float e = __fdiv_rn(0.0f - d, 0.2f);
    float mx = e;
#pragma unroll
    for (int off = 8; off > 0; off >>= 1) mx = fmaxf(mx, __shfl_xor(mx, off, 16));
    float ex = expf(__fsub_rn(e, mx));
    float sum = ex;
#pragma unroll
    for (int off = 8; off > 0; off >>= 1) sum = __fadd_rn(sum, __shfl_xor(sum, off, 16));
    float wgt = __fdiv_rn(ex, sum);
    float acc = 0.0f;
#pragma unroll
    for (int k = 0; k < NK; ++k) {
      float wk = __shfl(wgt, k, 64);
      int   nn = __shfl(nk, k, 64);
      acc = __fadd_rn(acc, __fmul_rn(wk, xT[((size_t)b * NN + nn) * NC + lane]));
    }
    tile[lane][ml] = acc;
  }
  __syncthreads();
  const int m0 = base & (NM - 1);
  for (int e2 = tid; e2 < 64 * 16; e2 += 256) {
    int c = e2 >> 4, ml = e2 & 15;
    xOut[((size_t)b * NC + c) * NM + m0 + ml] = tile[c][ml];
  }
}

extern "C" void kernel_launch(void* const* d_in, const int* in_sizes, int n_in,
                              void* d_out, int out_size, void* d_ws, size_t ws_size,
                              hipStream_t stream) {
  const float* x   = (const float*)d_in[0];
  const float* pos = (const float*)d_in[1];
  float* xOut   = (float*)d_out;
  float* posOut = xOut + (size_t)NB * NC * NM;

  char* w = (char*)d_ws;
  unsigned* startB = (unsigned*)(w + OFF_START);
  unsigned* sub1   = (unsigned*)(w + OFF_SUB1);
  unsigned* sub2   = (unsigned*)(w + OFF_SUB2);
  int*      idx    = (int*)(w + OFF_IDX);
  unsigned* v1     = (unsigned*)(w + OFF_V1);
  int*      knn    = (int*)(w + OFF_KNN);
  float*    xT     = (float*)(w + OFF_XT);

  hipLaunchKernelGGL(rng_setup, dim3(1), dim3(64), 0, stream, startB, sub1, sub2);
  hipLaunchKernelGGL(fps_kernel, dim3(NB), dim3(512), 0, stream, pos, startB, idx);
  hipLaunchKernelGGL(perm_kernel, dim3(2 * NB), dim3(1024), 0, stream, sub1, sub2, v1, idx);
  hipLaunchKernelGGL(possub_kernel, dim3((NB * 3 * NM + 255) / 256), dim3(256), 0, stream,
                     pos, idx, v1, posOut);
  hipLaunchKernelGGL(transpose_kernel, dim3(NN / 32, NC / 32, NB), dim3(32, 32), 0, stream,
                     x, xT);
  hipLaunchKernelGGL(knn_kernel, dim3(NB * NM / 4), dim3(256), 0, stream, pos, posOut, knn);
  hipLaunchKernelGGL(final_kernel, dim3(NB * NM / 16), dim3(256), 0, stream,
                     xT, pos, posOut, knn, xOut);
}